// Round 1
// baseline (232.820 us; speedup 1.0000x reference)
//
#include <hip/hip_runtime.h>
#include <stdint.h>

// Shapes are fixed by the reference: B=2, T=2048, C=1024, H=16, Dh=64.
#define B_   2
#define T_   2048
#define C_   1024
#define H_   16
#define BT   4096      // B_*T_
#define KDIM 1024      // inner dim of all projections

typedef unsigned short u16;
typedef __attribute__((ext_vector_type(8))) __bf16 bf16v8;   // 4 VGPR MFMA operand
typedef __attribute__((ext_vector_type(4))) float f32x4;     // MFMA accumulator

#define MFMA16(a, b, c) __builtin_amdgcn_mfma_f32_16x16x32_bf16((a), (b), (c), 0, 0, 0)

__device__ __forceinline__ u16 f2bf(float f) {
  union { float f; uint32_t u; } v; v.f = f;
  return (u16)((v.u + 0x7FFFu + ((v.u >> 16) & 1u)) >> 16);   // RNE
}

// async global->LDS, 16B per lane; LDS dest is wave-uniform base + lane*16
__device__ __forceinline__ void gload16(const void* g, void* l) {
  __builtin_amdgcn_global_load_lds((__attribute__((address_space(1))) void*)g,
                                   (__attribute__((address_space(3))) void*)l,
                                   16, 0, 0);
}

// ---------------------------------------------------------------- fp32->bf16
__global__ __launch_bounds__(256) void cvt_f32_bf16(const float* __restrict__ in,
                                                    u16* __restrict__ out, int n) {
  int i = (blockIdx.x * 256 + threadIdx.x) * 4;
  if (i + 3 < n) {
    float4 v = *(const float4*)(in + i);
    ushort4 o;
    o.x = f2bf(v.x); o.y = f2bf(v.y); o.z = f2bf(v.z); o.w = f2bf(v.w);
    *(ushort4*)(out + i) = o;
  }
}

// ---------------------------------------------------------------- GEMM (bt)
// C[M,N] = A[M,K] * Bm[N,K]^T.  M=4096, K=1024 fixed. 128x128 tile, BK=32,
// 4 waves, each wave owns a 64x64 quadrant as 4x4 16x16 fragments.
// EPI=0: write fp32 C.  EPI=1: N=3072 QKV fused; apply RoPE to q/k and
// scatter to (B,H,T,64) bf16 buffers.
template<int EPI, int NN>
__global__ __launch_bounds__(256) void gemm_bt(
    const u16* __restrict__ A, const u16* __restrict__ Bm,
    float* __restrict__ Cf,
    u16* __restrict__ qo, u16* __restrict__ ko, u16* __restrict__ vo,
    const float* __restrict__ cosT, const float* __restrict__ sinT)
{
  __shared__ __align__(16) u16 As[128 * 32];
  __shared__ __align__(16) u16 Bs[128 * 32];
  const int tid = threadIdx.x;
  const int lane = tid & 63;
  const int w = tid >> 6;
  const int wm = w >> 1, wn = w & 1;
  const int row0 = blockIdx.y * 128, col0 = blockIdx.x * 128;
  const int lmod = lane & 15, ldiv = lane >> 4;

  f32x4 acc[4][4] = {};

  for (int k0 = 0; k0 < KDIM; k0 += 32) {
    __syncthreads();   // previous tile's reads done
    // stage A,B tiles: 512 chunks of 16B each, 2 chunks/thread/tile
#pragma unroll
    for (int c = 0; c < 2; ++c) {
      const int chunk = c * 256 + tid;
      const int r = chunk >> 2, kc = chunk & 3;
      const int ldsb = (c * 256 + (tid & 192)) * 8;   // elements
      gload16(A  + (size_t)(row0 + r) * KDIM + k0 + kc * 8, As + ldsb);
      gload16(Bm + (size_t)(col0 + r) * KDIM + k0 + kc * 8, Bs + ldsb);
    }
    __syncthreads();   // drains vmcnt: tiles ready

    bf16v8 af[4], bfr[4];
#pragma unroll
    for (int mf = 0; mf < 4; ++mf)
      af[mf] = *(const bf16v8*)(As + (wm * 64 + mf * 16 + lmod) * 32 + ldiv * 8);
#pragma unroll
    for (int nf = 0; nf < 4; ++nf)
      bfr[nf] = *(const bf16v8*)(Bs + (wn * 64 + nf * 16 + lmod) * 32 + ldiv * 8);
#pragma unroll
    for (int mf = 0; mf < 4; ++mf)
#pragma unroll
      for (int nf = 0; nf < 4; ++nf)
        acc[mf][nf] = MFMA16(af[mf], bfr[nf], acc[mf][nf]);
  }

  if (EPI == 0) {
#pragma unroll
    for (int mf = 0; mf < 4; ++mf) {
      const int mbase = row0 + wm * 64 + mf * 16 + ldiv * 4;
#pragma unroll
      for (int nf = 0; nf < 4; ++nf) {
        const int n = col0 + wn * 64 + nf * 16 + lmod;
#pragma unroll
        for (int r = 0; r < 4; ++r)
          Cf[(size_t)(mbase + r) * NN + n] = acc[mf][nf][r];
      }
    }
  } else {
    // wave's 64-col block is head-aligned: all 64 dims of one head live in
    // this wave's acc; RoPE pair (d, d+-32) = fragments (nf, nf+-2), same lane.
    const int nb = col0 + wn * 64;
    const int proj = nb >> 10;            // 0=q 1=k 2=v
    const int hh = (nb & 1023) >> 6;      // head
    u16* dst = (proj == 0) ? qo : (proj == 1) ? ko : vo;
#pragma unroll
    for (int mf = 0; mf < 4; ++mf) {
#pragma unroll
      for (int r = 0; r < 4; ++r) {
        const int m = row0 + wm * 64 + mf * 16 + ldiv * 4 + r;
        const int b = m >> 11, t = m & 2047;
        u16* drow = dst + ((size_t)(b * H_ + hh) * T_ + t) * 64;
#pragma unroll
        for (int nf = 0; nf < 4; ++nf) {
          const int d = nf * 16 + lmod;
          float val = acc[mf][nf][r];
          if (proj < 2) {
            const float cs = cosT[t * 64 + d];
            const float sn = sinT[t * 64 + d];
            const float other = (nf < 2) ? acc[mf][nf + 2][r] : acc[mf][nf - 2][r];
            val = (nf < 2) ? (val * cs - other * sn) : (val * cs + other * sn);
          }
          drow[d] = f2bf(val);
        }
      }
    }
  }
}

// ---------------------------------------------------------------- V -> V^T
// v (BH, T, 64) -> vt (BH, 64, T); 64x64 LDS tiles, pad 72 for bank spread.
__global__ __launch_bounds__(256) void transpose_v(const u16* __restrict__ v,
                                                   u16* __restrict__ vt) {
  __shared__ __align__(16) u16 tile[64][72];
  const int bh = blockIdx.x >> 5;
  const int tb = (blockIdx.x & 31) << 6;
  const int tid = threadIdx.x;
#pragma unroll
  for (int c = 0; c < 2; ++c) {
    const int idx = c * 256 + tid;
    const int r = idx >> 3, col = (idx & 7) << 3;
    *(uint4*)&tile[r][col] = *(const uint4*)&v[((size_t)bh * T_ + tb + r) * 64 + col];
  }
  __syncthreads();
#pragma unroll
  for (int c = 0; c < 2; ++c) {
    const int idx = c * 256 + tid;
    const int d = idx >> 3, col = (idx & 7) << 3;
    u16 tmp[8];
#pragma unroll
    for (int j = 0; j < 8; ++j) tmp[j] = tile[col + j][d];
    *(uint4*)&vt[((size_t)bh * 64 + d) * T_ + tb + col] = *(uint4*)tmp;
  }
}

// ---------------------------------------------------------------- attention
// One block = (b,h, 64 q-rows). 4 waves x 16 q-rows. KV tiles of 64 staged in
// LDS (XOR-swizzled via pre-swizzled global source, rule #21). Online softmax
// wave-parallel over the 16 lanes that share a row. P re-fragmented via padded
// per-wave LDS for the PV MFMA.
__global__ __launch_bounds__(256) void attn_fwd(
    const u16* __restrict__ Q, const u16* __restrict__ K,
    const u16* __restrict__ Vt, u16* __restrict__ O)
{
  __shared__ __align__(16) u16 Kl[64 * 64];
  __shared__ __align__(16) u16 Vl[64 * 64];
  __shared__ __align__(16) u16 Pl[4][16][72];
  const int bi = blockIdx.x;
  const int bh = bi >> 5;
  const int qb = 31 - (bi & 31);          // heavy q-blocks dispatch first
  const int q0 = qb << 6;
  const int tid = threadIdx.x, lane = tid & 63, w = tid >> 6;
  const int lmod = lane & 15, ldiv = lane >> 4;
  const int qrow = q0 + w * 16;

  // Q fragments (held in registers for the whole block)
  bf16v8 aq[2];
  {
    const u16* qp = Q + ((size_t)bh * T_ + qrow + lmod) * 64;
    aq[0] = *(const bf16v8*)(qp + ldiv * 8);
    aq[1] = *(const bf16v8*)(qp + 32 + ldiv * 8);
  }

  float mrow[4] = {-1e30f, -1e30f, -1e30f, -1e30f};
  float lrow[4] = {0.f, 0.f, 0.f, 0.f};
  f32x4 oacc[4] = {};

  const int nblk = qb + 1;
  for (int sb = 0; sb < nblk; ++sb) {
    const int s0 = sb << 6;
    __syncthreads();                      // previous tile consumed
    // stage K (rows=key, 128B) and Vt (rows=d, 128B) tiles; source address
    // carries the inverse XOR swizzle so swizzled reads below are conflict-free
#pragma unroll
    for (int c = 0; c < 2; ++c) {
      const int chunk = c * 256 + tid;
      const int r = chunk >> 3;
      const int pb = ((chunk & 7) * 16) ^ ((r & 7) << 4);
      const int ldsb = (c * 256 + (tid & 192)) * 16;   // bytes
      gload16((const char*)(K  + ((size_t)bh * T_ + s0 + r) * 64) + pb, (char*)Kl + ldsb);
      gload16((const char*)(Vt + ((size_t)(bh * 64 + r)) * T_ + s0) + pb, (char*)Vl + ldsb);
    }
    __syncthreads();                      // tiles ready
    if (s0 > qrow + 15) continue;         // fully masked for this wave

    // S = Q K^T (scaled later); k-dim = Dh in 2 chunks of 32
    f32x4 sacc[4] = {};
#pragma unroll
    for (int kc = 0; kc < 2; ++kc) {
#pragma unroll
      for (int nf = 0; nf < 4; ++nf) {
        const int rr = nf * 16 + lmod;
        const int cb = (kc * 32 + ldiv * 8) * 2;
        const bf16v8 bk = *(const bf16v8*)((const char*)Kl + rr * 128 + (cb ^ ((rr & 7) << 4)));
        sacc[nf] = MFMA16(aq[kc], bk, sacc[nf]);
      }
    }
    // scale + causal mask
#pragma unroll
    for (int nf = 0; nf < 4; ++nf) {
      const int scol = s0 + nf * 16 + lmod;
#pragma unroll
      for (int r = 0; r < 4; ++r) {
        float sv = sacc[nf][r] * 0.125f;
        if (scol > qrow + ldiv * 4 + r) sv = -1e30f;
        sacc[nf][r] = sv;
      }
    }
    // online softmax; each row's 64 scores live in 16 lanes x 4 fragments
#pragma unroll
    for (int r = 0; r < 4; ++r) {
      float mx = fmaxf(fmaxf(sacc[0][r], sacc[1][r]), fmaxf(sacc[2][r], sacc[3][r]));
      mx = fmaxf(mx, __shfl_xor(mx, 1));
      mx = fmaxf(mx, __shfl_xor(mx, 2));
      mx = fmaxf(mx, __shfl_xor(mx, 4));
      mx = fmaxf(mx, __shfl_xor(mx, 8));
      const float mnew = fmaxf(mrow[r], mx);
      const float rescale = __expf(mrow[r] - mnew);
      mrow[r] = mnew;
      float rs = 0.f;
#pragma unroll
      for (int nf = 0; nf < 4; ++nf) {
        const float p = __expf(sacc[nf][r] - mnew);
        sacc[nf][r] = p;
        rs += p;
      }
      rs += __shfl_xor(rs, 1);
      rs += __shfl_xor(rs, 2);
      rs += __shfl_xor(rs, 4);
      rs += __shfl_xor(rs, 8);
      lrow[r] = lrow[r] * rescale + rs;
#pragma unroll
      for (int nf = 0; nf < 4; ++nf) oacc[nf][r] *= rescale;
    }
    // P (C-layout) -> per-wave LDS -> A-layout fragments
#pragma unroll
    for (int nf = 0; nf < 4; ++nf)
#pragma unroll
      for (int r = 0; r < 4; ++r)
        Pl[w][ldiv * 4 + r][nf * 16 + lmod] = f2bf(sacc[nf][r]);
    bf16v8 ap[2];
    ap[0] = *(const bf16v8*)&Pl[w][lmod][ldiv * 8];
    ap[1] = *(const bf16v8*)&Pl[w][lmod][32 + ldiv * 8];
    // O += P V  (B-operand from V^T tile, swizzled reads)
#pragma unroll
    for (int kc = 0; kc < 2; ++kc) {
#pragma unroll
      for (int nf = 0; nf < 4; ++nf) {
        const int rr = nf * 16 + lmod;
        const int cb = (kc * 32 + ldiv * 8) * 2;
        const bf16v8 bv = *(const bf16v8*)((const char*)Vl + rr * 128 + (cb ^ ((rr & 7) << 4)));
        oacc[nf] = MFMA16(ap[kc], bv, oacc[nf]);
      }
    }
  }

  const int b = bh >> 4, hh = bh & 15;
#pragma unroll
  for (int r = 0; r < 4; ++r) {
    const int t = qrow + ldiv * 4 + r;
    const float inv = 1.f / lrow[r];
    u16* orow = O + ((size_t)(b * T_ + t)) * C_ + hh * 64;
#pragma unroll
    for (int nf = 0; nf < 4; ++nf)
      orow[nf * 16 + lmod] = f2bf(oacc[nf][r] * inv);
  }
}

// ---------------------------------------------------------------- launch
extern "C" void kernel_launch(void* const* d_in, const int* in_sizes, int n_in,
                              void* d_out, int out_size, void* d_ws, size_t ws_size,
                              hipStream_t stream) {
  const float* x    = (const float*)d_in[0];
  const float* cosT = (const float*)d_in[1];
  const float* sinT = (const float*)d_in[2];
  // d_in[3] = mask (causal by construction, unused), d_in[4] = n_heads (=16)
  const float* Wq = (const float*)d_in[5];
  const float* Wk = (const float*)d_in[6];
  const float* Wv = (const float*)d_in[7];
  const float* Wo = (const float*)d_in[8];
  float* out = (float*)d_out;

  // workspace layout (48 MB total)
  char* ws = (char*)d_ws;
  u16* xb   = (u16*)(ws);                    // 4.19M elem bf16 x (later reused as attn_out)
  u16* wqkv = (u16*)(ws + 8388608);          // [Wq;Wk;Wv] bf16, 3M elem
  u16* wo   = (u16*)(ws + 14680064);         // Wo bf16
  u16* q    = (u16*)(ws + 16777216);         // (B,H,T,64) bf16, roped
  u16* k    = (u16*)(ws + 25165824);         // (B,H,T,64) bf16, roped
  u16* v    = (u16*)(ws + 33554432);         // (B,H,T,64) bf16
  u16* vt   = (u16*)(ws + 41943040);         // (B,H,64,T) bf16
  u16* aout = xb;                            // attention output reuses xb slot

  cvt_f32_bf16<<<4096, 256, 0, stream>>>(x, xb, BT * C_);
  cvt_f32_bf16<<<1024, 256, 0, stream>>>(Wq, wqkv,            C_ * C_);
  cvt_f32_bf16<<<1024, 256, 0, stream>>>(Wk, wqkv + 1048576,  C_ * C_);
  cvt_f32_bf16<<<1024, 256, 0, stream>>>(Wv, wqkv + 2097152,  C_ * C_);
  cvt_f32_bf16<<<1024, 256, 0, stream>>>(Wo, wo,              C_ * C_);

  // QKV projection + RoPE + scatter
  gemm_bt<1, 3072><<<dim3(24, 32), 256, 0, stream>>>(xb, wqkv, nullptr,
                                                     q, k, v, cosT, sinT);
  transpose_v<<<1024, 256, 0, stream>>>(v, vt);
  attn_fwd<<<1024, 256, 0, stream>>>(q, k, vt, aout);
  // output projection -> fp32
  gemm_bt<0, 1024><<<dim3(8, 32), 256, 0, stream>>>(aout, wo, out,
                                                    nullptr, nullptr, nullptr,
                                                    nullptr, nullptr);
}